// Round 15
// baseline (245.839 us; speedup 1.0000x reference)
//
#include <hip/hip_runtime.h>
#include <math.h>

#define QMAXF 32767.0f

typedef short short8v __attribute__((ext_vector_type(8)));
typedef float f32x4 __attribute__((ext_vector_type(4)));

__device__ __forceinline__ float clampf(float v, float lo, float hi) {
    return __builtin_amdgcn_fmed3f(v, lo, hi);
}
__device__ __forceinline__ float fq_code(float x, float s) {
    return clampf(rintf(x / s), -QMAXF, QMAXF);
}

// ---------------- weight prep + epilogue tables: 196 independent blocks ----------------
__device__ float block_scale(const float* w, int n, float* red) {
    float m = 0.f;
    for (int i = threadIdx.x; i < n; i += blockDim.x) m = fmaxf(m, fabsf(w[i]));
    red[threadIdx.x] = m; __syncthreads();
    for (int s = blockDim.x >> 1; s > 0; s >>= 1) {
        if ((int)threadIdx.x < s) red[threadIdx.x] = fmaxf(red[threadIdx.x], red[threadIdx.x + s]);
        __syncthreads();
    }
    float r = red[0]; __syncthreads();
    return fmaxf(r / QMAXF, 1e-8f);
}

__device__ void prep_16x16(const float* __restrict__ w, ushort* __restrict__ wqb,
                           float* __restrict__ wsb_slot, float* red) {
    float s = block_scale(w, 2304, red);
    if (threadIdx.x == 0) *wsb_slot = s;
    for (int i = threadIdx.x; i < 2304; i += 256) {
        int co = i / 144, rem = i % 144, cin = rem / 9, t = rem % 9;
        int wc = (int)fq_code(w[i], s);
        uint bh = __float_as_uint((float)(wc & ~127)) >> 16;
        uint bl = __float_as_uint((float)(wc & 127)) >> 16;
        int kb = cin >> 3, j = cin & 7;
        wqb[((t * 4 + kb) * 16 + co) * 8 + j]     = (ushort)bh;
        wqb[((t * 4 + 2 + kb) * 16 + co) * 8 + j] = (ushort)bl;
    }
}

// Tables: t1[xi+32768] = requant code after h-gelu (layer1, shift[0], rq=osc0/asc[1])
//         t2[...]      = same for layer2 (shift[1], rq=osc1/asc[2])
//         t3[...]      = h-gelu code k (layer3, shift[2]) for the pool path
// Built with the IDENTICAL float sequence as the previous in-kernel epilogue -> bit-exact.
__global__ void prep_kernel(const float* __restrict__ w1, const float* __restrict__ w2,
                            const float* __restrict__ w3, const float* __restrict__ wfc,
                            const float* __restrict__ asc, const float* __restrict__ shf,
                            float* __restrict__ wq1, ushort* __restrict__ wq2b,
                            ushort* __restrict__ wq3b, float* __restrict__ wqfc,
                            float* __restrict__ wsb, ushort* __restrict__ t1,
                            ushort* __restrict__ t2, short* __restrict__ t3) {
    __shared__ float red[256];
    const int which = blockIdx.x;
    if (which == 0) {
        float s = block_scale(w1, 144, red);   // [16][1][3][3] -> [tap][16], a0 folded
        float a0 = asc[0];
        for (int i = threadIdx.x; i < 144; i += 256) {
            int co = i / 9, r = i % 9;
            wq1[r * 16 + co] = fq_code(w1[i], s) * s * a0;
        }
    } else if (which == 1) {
        prep_16x16(w2, wq2b, wsb + 0, red);
    } else if (which == 2) {
        prep_16x16(w3, wq3b, wsb + 1, red);
    } else if (which == 3) {
        float s = block_scale(wfc, 160, red);
        for (int i = threadIdx.x; i < 160; i += 256) wqfc[i] = fq_code(wfc[i], s) * s;
    } else {
        const int tb = which - 4;            // 0..191
        const int tt = tb >> 6;              // table id 0..2
        const int base = ((tb & 63) * 256 + (int)threadIdx.x) * 4;
        const float shv = clampf(rintf(shf[tt]), 4.f, 12.f);
        const float scv = exp2f(shv), oscv = exp2f(-shv);
        const float three = 3.f * scv, six = 6.f * scv;
        const float r6v = 1.0f / six;
        const float rq = oscv / asc[tt + 1];
        (void)scv;
#pragma unroll
        for (int i = 0; i < 4; i++) {
            float xi = (float)(base + i - 32768);
            float slope = rintf(xi * 1.703125f);
            float gate = clampf(slope + three, 0.f, six);
            float k = clampf(rintf(xi * gate * r6v), -QMAXF, QMAXF);
            if (tt == 0)
                t1[base + i] = (ushort)(short)(int)clampf(rintf(k * rq), -QMAXF, QMAXF);
            else if (tt == 1)
                t2[base + i] = (ushort)(short)(int)clampf(rintf(k * rq), -QMAXF, QMAXF);
            else
                t3[base + i] = (short)(int)k;
        }
    }
}

// ---------------- conv1: 1->16 ch (VALU), 8 rows x 112 cols, 2px x 8co x 2 passes ----------------
__global__ __launch_bounds__(448, 4) void conv1_kernel(const float* __restrict__ x,
        const float* __restrict__ wq, const float* __restrict__ bias,
        const float* __restrict__ asc, const float* __restrict__ shf,
        const ushort* __restrict__ t1, ushort* __restrict__ out) {
    const int bid = blockIdx.x;
    const int b = bid / 56, rem = bid % 56, rg = rem >> 1, chh = rem & 1;
    const int r0 = rg * 8, c0 = chh * 112;
    const int tid = threadIdx.x;
    __shared__ alignas(16) short lx[10 * 120];   // x[ic] at col (ic-c0+1); row stride 120
    __shared__ alignas(16) float lw[144];
    __shared__ float lbsc[16];
    const float a0 = asc[0];
    const float r0a = 1.0f / a0;
    const float sh = clampf(rintf(shf[0]), 4.f, 12.f);
    const float sc = exp2f(sh);
    const float* xb = x + (size_t)b * 50176;
    for (int i = tid; i < 1140; i += 448) {
        int r = i / 114, cc = i - r * 114;
        int ir = r0 - 1 + r, ic = c0 - 1 + cc;
        float v = ((unsigned)ir < 224u && (unsigned)ic < 224u) ? xb[ir * 224 + ic] : 0.f;
        lx[r * 120 + cc] = (short)clampf(rintf(v * r0a), -QMAXF, QMAXF);
    }
    for (int i = tid; i < 144; i += 448) lw[i] = wq[i];
    if (tid < 16) lbsc[tid] = bias[tid] * sc;
    __syncthreads();
    const int row = tid / 56, pc = (tid - row * 56) * 2;
    const int orow = r0 + row;
    const size_t obase = ((size_t)b * 224 + orow) * 224 + c0 + pc;   // pixel index
#pragma unroll
    for (int cop = 0; cop < 2; cop++) {
        float acc[2][8];
#pragma unroll
        for (int p = 0; p < 2; p++)
#pragma unroll
            for (int j = 0; j < 8; j++) acc[p][j] = 0.f;
#pragma unroll
        for (int ky = 0; ky < 3; ky++) {
            const short* rp = lx + (row + ky) * 120 + pc;
            int i0 = *(const int*)(rp);        // x[pc-1], x[pc]
            int i1 = *(const int*)(rp + 2);    // x[pc+1], x[pc+2]
            float xf[4];
            xf[0] = (float)(short)(i0 & 0xffff);
            xf[1] = (float)(i0 >> 16);
            xf[2] = (float)(short)(i1 & 0xffff);
            xf[3] = (float)(i1 >> 16);
#pragma unroll
            for (int kx = 0; kx < 3; kx++) {
                const float* wp = &lw[(ky * 3 + kx) * 16 + cop * 8];
#pragma unroll
                for (int p = 0; p < 2; p++) {
                    float xv = xf[p + kx];
#pragma unroll
                    for (int j = 0; j < 8; j++)
                        acc[p][j] = fmaf(xv, wp[j], acc[p][j]);
                }
            }
        }
#pragma unroll
        for (int p = 0; p < 2; p++) {
            uint pk[4];
#pragma unroll
            for (int j = 0; j < 8; j++) {
                float xi = clampf(rintf(fmaf(acc[p][j], sc, lbsc[cop * 8 + j])), -32768.f, 32767.f);
                uint cd = t1[(int)xi + 32768];
                if (j & 1) pk[j >> 1] |= cd << 16;
                else       pk[j >> 1] = cd;
            }
            *(uint4*)(out + (obase + p) * 16 + cop * 8) = make_uint4(pk[0], pk[1], pk[2], pk[3]);
        }
    }
}

// ---------------- conv2/conv3: MFMA implicit GEMM (D = W * X), 4 rows x {96,96,32} cols ----------------
// R10 body (measured best: VGPR 56, FETCH 80MB, conflicts 0) with the h-gelu+requant
// epilogue chain replaced by a table gather on xi (tq for requant, tk for pool-k).
// LDS x: entries e = row*98 + col; entry = 64B = 4 chunks of 8 bf16
// (0: xh cin0-7, 1: xh cin8-15, 2: xl cin0-7, 3: xl cin8-15); chunk c at slot c^((e>>1)&3).
// rot invariant under +96-entry ky step (Ab + 3072*ky shorts) and +16-entry cg step.
template <bool POOL>
__global__ __launch_bounds__(256, 3) void conv16_kernel(
        const ushort* __restrict__ in, const ushort* __restrict__ wq,
        const float* __restrict__ bias, const float* __restrict__ asc,
        const float* __restrict__ shf, const float* __restrict__ wsb,
        const ushort* __restrict__ tq, const short* __restrict__ tk,
        ushort* __restrict__ out, float* __restrict__ partial,
        int aidx, int sidx, int widx) {
    const int bid = blockIdx.x;
    const int b = bid / 168, t3 = bid % 168, rg = t3 / 3, cidx = t3 % 3;
    const int r0 = rg * 4, c0 = cidx * 96;
    const int ncg = (cidx < 2) ? 6 : 2;
    const int tid = threadIdx.x;
    const int l = tid & 63, w = tid >> 6;
    const int l15 = l & 15, lk = l >> 4;

    __shared__ alignas(16) ushort lsx[588 * 32];        // 37,632 B (6 rows x 98 cols)
    __shared__ float lred[4][16];

    const float ain = asc[aidx];
    const float wsc = wsb[widx];
    const float sh = clampf(rintf(shf[sidx]), 4.f, 12.f);
    const float sc = exp2f(sh), osc = exp2f(-sh);
    const float gs2 = (ain * wsc) * sc;
    f32x4 bscv;
    bscv[0] = bias[lk * 4 + 0] * sc;
    bscv[1] = bias[lk * 4 + 1] * sc;
    bscv[2] = bias[lk * 4 + 2] * sc;
    bscv[3] = bias[lk * 4 + 3] * sc;

    // ---- W fragments (A operand of mfma): pass1 [wh|wl], pass2 [wl|wh] ----
    short8v B1[9], B2[9];
#pragma unroll
    for (int t = 0; t < 9; t++) {
        B1[t] = *(const short8v*)(wq + ((t * 4 + lk) * 16 + l15) * 8);
        B2[t] = *(const short8v*)(wq + ((t * 4 + (lk ^ 2)) * 16 + l15) * 8);
    }

    // ---- stage x tile: 6 rows x 98 cols; RTZ bf16 hi/lo split (exact) ----
#pragma unroll
    for (int it = 0; it < 3; it++) {
        int e = tid + it * 256;
        if (e < 588) {
            int r = e / 98, cc = e - r * 98;
            int ir = r0 - 1 + r, ic = c0 - 1 + cc;
            uint4 va = make_uint4(0u, 0u, 0u, 0u), vb = make_uint4(0u, 0u, 0u, 0u);
            if ((unsigned)ir < 224u && (unsigned)ic < 224u) {
                const uint4* src = (const uint4*)(in + (((size_t)b * 224 + ir) * 224 + ic) * 16);
                va = src[0]; vb = src[1];
            }
            uint uu[8] = {va.x, va.y, va.z, va.w, vb.x, vb.y, vb.z, vb.w};
            uint hi[8], lo[8];
#pragma unroll
            for (int i = 0; i < 8; i++) {
                int e0 = (int)(short)(uu[i] & 0xffffu);
                int e1 = (int)uu[i] >> 16;
                float f0 = (float)e0, f1 = (float)e1;
                uint h0 = __float_as_uint(f0) & 0xffff0000u;
                uint h1 = __float_as_uint(f1) & 0xffff0000u;
                float l0f = f0 - __uint_as_float(h0);   // exact, fits bf16
                float l1f = f1 - __uint_as_float(h1);
                hi[i] = __builtin_amdgcn_perm(h1, h0, 0x07060302);
                lo[i] = __builtin_amdgcn_perm(__float_as_uint(l1f), __float_as_uint(l0f), 0x07060302);
            }
            int rot = (e >> 1) & 3;
            ushort* eb = lsx + e * 32;
            *(uint4*)(eb + ((0 ^ rot) << 3)) = make_uint4(hi[0], hi[1], hi[2], hi[3]);
            *(uint4*)(eb + ((1 ^ rot) << 3)) = make_uint4(hi[4], hi[5], hi[6], hi[7]);
            *(uint4*)(eb + ((2 ^ rot) << 3)) = make_uint4(lo[0], lo[1], lo[2], lo[3]);
            *(uint4*)(eb + ((3 ^ rot) << 3)) = make_uint4(lo[4], lo[5], lo[6], lo[7]);
        }
    }
    __syncthreads();

    // ---- per-lane swizzled base pointers (rot invariant under +96-entry ky step
    //      and +16-entry cg step); indexed with literals only ----
    const ushort* Ab[7];
#pragma unroll
    for (int m = 0; m < 7; m++) {
        int e = w * 98 + l15 + m;
        Ab[m] = lsx + e * 32 + ((lk ^ ((e >> 1) & 3)) << 3);
    }

    f32x4 wsum = {0.f, 0.f, 0.f, 0.f};
    const int orow = r0 + w;
    ushort* opb = out + (((size_t)b * 224 + orow) * 224 + c0 + l15) * 16 + lk * 4;

    const f32x4 Z = {0.f, 0.f, 0.f, 0.f};

    for (int cg = 0; cg < ncg; cg++) {
        f32x4 acc0 = Z, acc1 = Z;
#pragma unroll
        for (int ky = 0; ky < 3; ky++) {
#pragma unroll
            for (int kx = 0; kx < 3; kx++) {
                short8v a = *(const short8v*)(Ab[2 * ky + kx] + 3072 * ky + 512 * cg);
                int t = ky * 3 + kx;
                if (t & 1) {
                    acc1 = __builtin_amdgcn_mfma_f32_16x16x32_bf16(B1[t], a, acc1, 0, 0, 0);
                    acc1 = __builtin_amdgcn_mfma_f32_16x16x32_bf16(B2[t], a, acc1, 0, 0, 0);
                } else {
                    acc0 = __builtin_amdgcn_mfma_f32_16x16x32_bf16(B1[t], a, acc0, 0, 0, 0);
                    acc0 = __builtin_amdgcn_mfma_f32_16x16x32_bf16(B2[t], a, acc0, 0, 0, 0);
                }
            }
        }
        if (!POOL) {
            uint cd[4];
#pragma unroll
            for (int r = 0; r < 4; r++) {
                float s = acc0[r] + acc1[r];
                float xi = clampf(rintf(fmaf(s, gs2, bscv[r])), -32768.f, 32767.f);
                cd[r] = tq[(int)xi + 32768];
            }
            uint2 st;
            st.x = cd[0] | (cd[1] << 16);
            st.y = cd[2] | (cd[3] << 16);
            *(uint2*)(opb + cg * 256) = st;
        } else {
#pragma unroll
            for (int r = 0; r < 4; r++) {
                float s = acc0[r] + acc1[r];
                float xi = clampf(rintf(fmaf(s, gs2, bscv[r])), -32768.f, 32767.f);
                wsum[r] += (float)tk[(int)xi + 32768];
            }
        }
    }

    if (POOL) {
#pragma unroll
        for (int r = 0; r < 4; r++) {
            float v = wsum[r] * osc;
            v += __shfl_xor(v, 1);
            v += __shfl_xor(v, 2);
            v += __shfl_xor(v, 4);
            v += __shfl_xor(v, 8);
            if (l15 == 0) lred[w][lk * 4 + r] = v;
        }
        __syncthreads();
        if (tid < 16) {
            partial[((size_t)b * 168 + t3) * 16 + tid] =
                lred[0][tid] + lred[1][tid] + lred[2][tid] + lred[3][tid];
        }
    }
}

// ---------------- pool-reduce + quantized FC ----------------
__global__ __launch_bounds__(1024) void fc_kernel(const float* __restrict__ partial,
        const float* __restrict__ wq, const float* __restrict__ fb,
        const float* __restrict__ asc, float* __restrict__ out) {
    __shared__ float xq[64][16];
    const int t = threadIdx.x;
    const float a3 = asc[3];
    {
        int b = t >> 4, c = t & 15;
        const float* p = partial + ((size_t)b * 168) * 16 + c;
        float s = 0.f;
#pragma unroll 8
        for (int i = 0; i < 168; i++) s += p[i * 16];
        float pooled = s / 50176.0f;
        xq[b][c] = fq_code(pooled, a3) * a3;
    }
    __syncthreads();
    if (t < 640) {
        int b = t / 10, o = t - (t / 10) * 10;
        float s = 0.f;
#pragma unroll
        for (int c = 0; c < 16; c++) s += xq[b][c] * wq[o * 16 + c];
        out[t] = s + fb[o];
    }
}

extern "C" void kernel_launch(void* const* d_in, const int* in_sizes, int n_in,
                              void* d_out, int out_size, void* d_ws, size_t ws_size,
                              hipStream_t stream) {
    const float* x   = (const float*)d_in[0];
    const float* c1w = (const float*)d_in[1];
    const float* c1b = (const float*)d_in[2];
    const float* c2w = (const float*)d_in[3];
    const float* c2b = (const float*)d_in[4];
    const float* c3w = (const float*)d_in[5];
    const float* c3b = (const float*)d_in[6];
    const float* fcw = (const float*)d_in[7];
    const float* fcb = (const float*)d_in[8];
    const float* asc = (const float*)d_in[9];
    const float* shf = (const float*)d_in[10];

    char* ws = (char*)d_ws;
    size_t off = 0;
    auto alloc = [&](size_t bytes) -> void* {
        void* p = ws + off;
        off = (off + bytes + 255) & ~(size_t)255;
        return p;
    };
    float*  wq1     = (float*)alloc(144 * 4);
    ushort* wq2b    = (ushort*)alloc(4608 * 2);
    ushort* wq3b    = (ushort*)alloc(4608 * 2);
    float*  wqfc    = (float*)alloc(160 * 4);
    float*  wsb     = (float*)alloc(4 * 4);
    ushort* t1      = (ushort*)alloc(65536 * 2);
    ushort* t2      = (ushort*)alloc(65536 * 2);
    short*  t3      = (short*)alloc(65536 * 2);
    float*  partial = (float*)alloc(64 * 168 * 16 * 4);
    ushort* actA    = (ushort*)alloc(51380224ull * 2);
    ushort* actB    = (ushort*)alloc(51380224ull * 2);

    prep_kernel<<<196, 256, 0, stream>>>(c1w, c2w, c3w, fcw, asc, shf,
                                         wq1, wq2b, wq3b, wqfc, wsb, t1, t2, t3);
    conv1_kernel<<<3584, 448, 0, stream>>>(x, wq1, c1b, asc, shf, t1, actA);
    conv16_kernel<false><<<10752, 256, 0, stream>>>(actA, wq2b, c2b, asc, shf, wsb,
                                                    t2, nullptr, actB, nullptr, 1, 1, 0);
    conv16_kernel<true ><<<10752, 256, 0, stream>>>(actB, wq3b, c3b, asc, shf, wsb,
                                                    nullptr, t3, nullptr, partial, 2, 2, 1);
    fc_kernel<<<1, 1024, 0, stream>>>(partial, wqfc, fcb, asc, (float*)d_out);
}

// Round 16
// 225.466 us; speedup vs baseline: 1.0904x; 1.0904x over previous
//
#include <hip/hip_runtime.h>
#include <math.h>

#define QMAXF 32767.0f

typedef short short8v __attribute__((ext_vector_type(8)));
typedef float f32x4 __attribute__((ext_vector_type(4)));

__device__ __forceinline__ float clampf(float v, float lo, float hi) {
    return __builtin_amdgcn_fmed3f(v, lo, hi);
}
__device__ __forceinline__ float fq_code(float x, float s) {
    return clampf(rintf(x / s), -QMAXF, QMAXF);
}

// ---------------- weight prep: 4 independent blocks ----------------
__device__ float block_scale(const float* w, int n, float* red) {
    float m = 0.f;
    for (int i = threadIdx.x; i < n; i += blockDim.x) m = fmaxf(m, fabsf(w[i]));
    red[threadIdx.x] = m; __syncthreads();
    for (int s = blockDim.x >> 1; s > 0; s >>= 1) {
        if ((int)threadIdx.x < s) red[threadIdx.x] = fmaxf(red[threadIdx.x], red[threadIdx.x + s]);
        __syncthreads();
    }
    float r = red[0]; __syncthreads();
    return fmaxf(r / QMAXF, 1e-8f);
}

__device__ void prep_16x16(const float* __restrict__ w, ushort* __restrict__ wqb,
                           float* __restrict__ wsb_slot, float* red) {
    float s = block_scale(w, 2304, red);
    if (threadIdx.x == 0) *wsb_slot = s;
    for (int i = threadIdx.x; i < 2304; i += 256) {
        int co = i / 144, rem = i % 144, cin = rem / 9, t = rem % 9;
        int wc = (int)fq_code(w[i], s);
        uint bh = __float_as_uint((float)(wc & ~127)) >> 16;
        uint bl = __float_as_uint((float)(wc & 127)) >> 16;
        int kb = cin >> 3, j = cin & 7;
        wqb[((t * 4 + kb) * 16 + co) * 8 + j]     = (ushort)bh;
        wqb[((t * 4 + 2 + kb) * 16 + co) * 8 + j] = (ushort)bl;
    }
}

__global__ void prep_kernel(const float* __restrict__ w1, const float* __restrict__ w2,
                            const float* __restrict__ w3, const float* __restrict__ wfc,
                            const float* __restrict__ asc,
                            float* __restrict__ wq1, ushort* __restrict__ wq2b,
                            ushort* __restrict__ wq3b, float* __restrict__ wqfc,
                            float* __restrict__ wsb) {
    __shared__ float red[256];
    const int which = blockIdx.x;
    if (which == 0) {
        float s = block_scale(w1, 144, red);   // [16][1][3][3] -> [tap][16], a0 folded
        float a0 = asc[0];
        for (int i = threadIdx.x; i < 144; i += 256) {
            int co = i / 9, r = i % 9;
            wq1[r * 16 + co] = fq_code(w1[i], s) * s * a0;
        }
    } else if (which == 1) {
        prep_16x16(w2, wq2b, wsb + 0, red);
    } else if (which == 2) {
        prep_16x16(w3, wq3b, wsb + 1, red);
    } else {
        float s = block_scale(wfc, 160, red);
        for (int i = threadIdx.x; i < 160; i += 256) wqfc[i] = fq_code(wfc[i], s) * s;
    }
}

// ---------------- conv1: 1->16 ch (VALU), 8 rows x 112 cols, 2px x 8co x 2 passes ----------------
__global__ __launch_bounds__(448, 4) void conv1_kernel(const float* __restrict__ x,
        const float* __restrict__ wq, const float* __restrict__ bias,
        const float* __restrict__ asc, const float* __restrict__ shf,
        ushort* __restrict__ out) {
    const int bid = blockIdx.x;
    const int b = bid / 56, rem = bid % 56, rg = rem >> 1, chh = rem & 1;
    const int r0 = rg * 8, c0 = chh * 112;
    const int tid = threadIdx.x;
    __shared__ alignas(16) short lx[10 * 120];   // x[ic] at col (ic-c0+1); row stride 120
    __shared__ alignas(16) float lw[144];
    __shared__ float lbsc[16];
    const float a0 = asc[0], a1 = asc[1];
    const float r0a = 1.0f / a0;
    const float sh = clampf(rintf(shf[0]), 4.f, 12.f);
    const float sc = exp2f(sh), osc = exp2f(-sh);
    const float three = 3.f * sc, six = 6.f * sc;
    const float r6v = 1.0f / six;
    const float rq1 = osc / a1;
    const float* xb = x + (size_t)b * 50176;
    for (int i = tid; i < 1140; i += 448) {
        int r = i / 114, cc = i - r * 114;
        int ir = r0 - 1 + r, ic = c0 - 1 + cc;
        float v = ((unsigned)ir < 224u && (unsigned)ic < 224u) ? xb[ir * 224 + ic] : 0.f;
        lx[r * 120 + cc] = (short)clampf(rintf(v * r0a), -QMAXF, QMAXF);
    }
    for (int i = tid; i < 144; i += 448) lw[i] = wq[i];
    if (tid < 16) lbsc[tid] = bias[tid] * sc;
    __syncthreads();
    const int row = tid / 56, pc = (tid - row * 56) * 2;
    const int orow = r0 + row;
    const size_t obase = ((size_t)b * 224 + orow) * 224 + c0 + pc;   // pixel index
#pragma unroll
    for (int cop = 0; cop < 2; cop++) {
        float acc[2][8];
#pragma unroll
        for (int p = 0; p < 2; p++)
#pragma unroll
            for (int j = 0; j < 8; j++) acc[p][j] = 0.f;
#pragma unroll
        for (int ky = 0; ky < 3; ky++) {
            const short* rp = lx + (row + ky) * 120 + pc;
            int i0 = *(const int*)(rp);        // x[pc-1], x[pc]
            int i1 = *(const int*)(rp + 2);    // x[pc+1], x[pc+2]
            float xf[4];
            xf[0] = (float)(short)(i0 & 0xffff);
            xf[1] = (float)(i0 >> 16);
            xf[2] = (float)(short)(i1 & 0xffff);
            xf[3] = (float)(i1 >> 16);
#pragma unroll
            for (int kx = 0; kx < 3; kx++) {
                const float* wp = &lw[(ky * 3 + kx) * 16 + cop * 8];
#pragma unroll
                for (int p = 0; p < 2; p++) {
                    float xv = xf[p + kx];
#pragma unroll
                    for (int j = 0; j < 8; j++)
                        acc[p][j] = fmaf(xv, wp[j], acc[p][j]);
                }
            }
        }
#pragma unroll
        for (int p = 0; p < 2; p++) {
            uint pk[4];
#pragma unroll
            for (int j = 0; j < 8; j++) {
                float xi = clampf(rintf(fmaf(acc[p][j], sc, lbsc[cop * 8 + j])), -32768.f, 32767.f);
                float slope = rintf(xi * 1.703125f);
                float gate = clampf(slope + three, 0.f, six);
                float k = clampf(rintf(xi * gate * r6v), -QMAXF, QMAXF);
                int cd = (int)clampf(rintf(k * rq1), -QMAXF, QMAXF);
                if (j & 1) pk[j >> 1] |= ((uint)cd) << 16;
                else       pk[j >> 1] = (uint)cd & 0xffffu;
            }
            *(uint4*)(out + (obase + p) * 16 + cop * 8) = make_uint4(pk[0], pk[1], pk[2], pk[3]);
        }
    }
}

// ---------------- conv2/conv3: MFMA implicit GEMM (D = W * X), 4 rows x {96,96,32} cols ----------------
// R10 configuration (measured best: conv16 88.6us, VGPR 56, FETCH 80MB, conflicts 0).
// LDS x: entries e = row*98 + col; entry = 64B = 4 chunks of 8 bf16
// (0: xh cin0-7, 1: xh cin8-15, 2: xl cin0-7, 3: xl cin8-15); chunk c at slot c^((e>>1)&3).
// rot invariant under +96-entry ky step (Ab + 3072*ky shorts) and +16-entry cg step.
template <bool POOL>
__global__ __launch_bounds__(256, 3) void conv16_kernel(
        const ushort* __restrict__ in, const ushort* __restrict__ wq,
        const float* __restrict__ bias, const float* __restrict__ asc,
        const float* __restrict__ shf, const float* __restrict__ wsb,
        ushort* __restrict__ out, float* __restrict__ partial,
        int aidx, int sidx, int widx) {
    const int bid = blockIdx.x;
    const int b = bid / 168, t3 = bid % 168, rg = t3 / 3, cidx = t3 % 3;
    const int r0 = rg * 4, c0 = cidx * 96;
    const int ncg = (cidx < 2) ? 6 : 2;
    const int tid = threadIdx.x;
    const int l = tid & 63, w = tid >> 6;
    const int l15 = l & 15, lk = l >> 4;

    __shared__ alignas(16) ushort lsx[588 * 32];        // 37,632 B (6 rows x 98 cols)
    __shared__ float lred[4][16];

    const float ain = asc[aidx];
    const float anext = asc[aidx + 1];
    const float wsc = wsb[widx];
    const float sh = clampf(rintf(shf[sidx]), 4.f, 12.f);
    const float sc = exp2f(sh), osc = exp2f(-sh);
    const float three = 3.f * sc, six = 6.f * sc;
    const float gs2 = (ain * wsc) * sc;
    const float r6v = 1.0f / six;
    const float rq = osc / anext;
    f32x4 bscv;
    bscv[0] = bias[lk * 4 + 0] * sc;
    bscv[1] = bias[lk * 4 + 1] * sc;
    bscv[2] = bias[lk * 4 + 2] * sc;
    bscv[3] = bias[lk * 4 + 3] * sc;

    // ---- W fragments (A operand of mfma): pass1 [wh|wl], pass2 [wl|wh] ----
    short8v B1[9], B2[9];
#pragma unroll
    for (int t = 0; t < 9; t++) {
        B1[t] = *(const short8v*)(wq + ((t * 4 + lk) * 16 + l15) * 8);
        B2[t] = *(const short8v*)(wq + ((t * 4 + (lk ^ 2)) * 16 + l15) * 8);
    }

    // ---- stage x tile: 6 rows x 98 cols; RTZ bf16 hi/lo split (exact) ----
#pragma unroll
    for (int it = 0; it < 3; it++) {
        int e = tid + it * 256;
        if (e < 588) {
            int r = e / 98, cc = e - r * 98;
            int ir = r0 - 1 + r, ic = c0 - 1 + cc;
            uint4 va = make_uint4(0u, 0u, 0u, 0u), vb = make_uint4(0u, 0u, 0u, 0u);
            if ((unsigned)ir < 224u && (unsigned)ic < 224u) {
                const uint4* src = (const uint4*)(in + (((size_t)b * 224 + ir) * 224 + ic) * 16);
                va = src[0]; vb = src[1];
            }
            uint uu[8] = {va.x, va.y, va.z, va.w, vb.x, vb.y, vb.z, vb.w};
            uint hi[8], lo[8];
#pragma unroll
            for (int i = 0; i < 8; i++) {
                int e0 = (int)(short)(uu[i] & 0xffffu);
                int e1 = (int)uu[i] >> 16;
                float f0 = (float)e0, f1 = (float)e1;
                uint h0 = __float_as_uint(f0) & 0xffff0000u;
                uint h1 = __float_as_uint(f1) & 0xffff0000u;
                float l0f = f0 - __uint_as_float(h0);   // exact, fits bf16
                float l1f = f1 - __uint_as_float(h1);
                hi[i] = __builtin_amdgcn_perm(h1, h0, 0x07060302);
                lo[i] = __builtin_amdgcn_perm(__float_as_uint(l1f), __float_as_uint(l0f), 0x07060302);
            }
            int rot = (e >> 1) & 3;
            ushort* eb = lsx + e * 32;
            *(uint4*)(eb + ((0 ^ rot) << 3)) = make_uint4(hi[0], hi[1], hi[2], hi[3]);
            *(uint4*)(eb + ((1 ^ rot) << 3)) = make_uint4(hi[4], hi[5], hi[6], hi[7]);
            *(uint4*)(eb + ((2 ^ rot) << 3)) = make_uint4(lo[0], lo[1], lo[2], lo[3]);
            *(uint4*)(eb + ((3 ^ rot) << 3)) = make_uint4(lo[4], lo[5], lo[6], lo[7]);
        }
    }
    __syncthreads();

    // ---- per-lane swizzled base pointers (rot invariant under +96-entry ky step
    //      and +16-entry cg step); indexed with literals only ----
    const ushort* Ab[7];
#pragma unroll
    for (int m = 0; m < 7; m++) {
        int e = w * 98 + l15 + m;
        Ab[m] = lsx + e * 32 + ((lk ^ ((e >> 1) & 3)) << 3);
    }

    f32x4 wsum = {0.f, 0.f, 0.f, 0.f};
    const int orow = r0 + w;
    ushort* opb = out + (((size_t)b * 224 + orow) * 224 + c0 + l15) * 16 + lk * 4;

    const f32x4 Z = {0.f, 0.f, 0.f, 0.f};

    for (int cg = 0; cg < ncg; cg++) {
        f32x4 acc0 = Z, acc1 = Z;
#pragma unroll
        for (int ky = 0; ky < 3; ky++) {
#pragma unroll
            for (int kx = 0; kx < 3; kx++) {
                short8v a = *(const short8v*)(Ab[2 * ky + kx] + 3072 * ky + 512 * cg);
                int t = ky * 3 + kx;
                if (t & 1) {
                    acc1 = __builtin_amdgcn_mfma_f32_16x16x32_bf16(B1[t], a, acc1, 0, 0, 0);
                    acc1 = __builtin_amdgcn_mfma_f32_16x16x32_bf16(B2[t], a, acc1, 0, 0, 0);
                } else {
                    acc0 = __builtin_amdgcn_mfma_f32_16x16x32_bf16(B1[t], a, acc0, 0, 0, 0);
                    acc0 = __builtin_amdgcn_mfma_f32_16x16x32_bf16(B2[t], a, acc0, 0, 0, 0);
                }
            }
        }
        if (!POOL) {
            int cd[4];
#pragma unroll
            for (int r = 0; r < 4; r++) {
                float s = acc0[r] + acc1[r];
                float xi = clampf(rintf(fmaf(s, gs2, bscv[r])), -32768.f, 32767.f);
                float slope = rintf(xi * 1.703125f);
                float gate = clampf(slope + three, 0.f, six);
                float k = clampf(rintf(xi * gate * r6v), -QMAXF, QMAXF);
                cd[r] = (int)clampf(rintf(k * rq), -QMAXF, QMAXF);
            }
            uint2 st;
            st.x = ((uint)cd[0] & 0xffffu) | ((uint)cd[1] << 16);
            st.y = ((uint)cd[2] & 0xffffu) | ((uint)cd[3] << 16);
            *(uint2*)(opb + cg * 256) = st;
        } else {
#pragma unroll
            for (int r = 0; r < 4; r++) {
                float s = acc0[r] + acc1[r];
                float xi = clampf(rintf(fmaf(s, gs2, bscv[r])), -32768.f, 32767.f);
                float slope = rintf(xi * 1.703125f);
                float gate = clampf(slope + three, 0.f, six);
                float k = clampf(rintf(xi * gate * r6v), -QMAXF, QMAXF);
                wsum[r] += k;
            }
        }
    }

    if (POOL) {
#pragma unroll
        for (int r = 0; r < 4; r++) {
            float v = wsum[r] * osc;
            v += __shfl_xor(v, 1);
            v += __shfl_xor(v, 2);
            v += __shfl_xor(v, 4);
            v += __shfl_xor(v, 8);
            if (l15 == 0) lred[w][lk * 4 + r] = v;
        }
        __syncthreads();
        if (tid < 16) {
            partial[((size_t)b * 168 + t3) * 16 + tid] =
                lred[0][tid] + lred[1][tid] + lred[2][tid] + lred[3][tid];
        }
    }
}

// ---------------- pool-reduce + quantized FC ----------------
__global__ __launch_bounds__(1024) void fc_kernel(const float* __restrict__ partial,
        const float* __restrict__ wq, const float* __restrict__ fb,
        const float* __restrict__ asc, float* __restrict__ out) {
    __shared__ float xq[64][16];
    const int t = threadIdx.x;
    const float a3 = asc[3];
    {
        int b = t >> 4, c = t & 15;
        const float* p = partial + ((size_t)b * 168) * 16 + c;
        float s = 0.f;
#pragma unroll 8
        for (int i = 0; i < 168; i++) s += p[i * 16];
        float pooled = s / 50176.0f;
        xq[b][c] = fq_code(pooled, a3) * a3;
    }
    __syncthreads();
    if (t < 640) {
        int b = t / 10, o = t - (t / 10) * 10;
        float s = 0.f;
#pragma unroll
        for (int c = 0; c < 16; c++) s += xq[b][c] * wq[o * 16 + c];
        out[t] = s + fb[o];
    }
}

extern "C" void kernel_launch(void* const* d_in, const int* in_sizes, int n_in,
                              void* d_out, int out_size, void* d_ws, size_t ws_size,
                              hipStream_t stream) {
    const float* x   = (const float*)d_in[0];
    const float* c1w = (const float*)d_in[1];
    const float* c1b = (const float*)d_in[2];
    const float* c2w = (const float*)d_in[3];
    const float* c2b = (const float*)d_in[4];
    const float* c3w = (const float*)d_in[5];
    const float* c3b = (const float*)d_in[6];
    const float* fcw = (const float*)d_in[7];
    const float* fcb = (const float*)d_in[8];
    const float* asc = (const float*)d_in[9];
    const float* shf = (const float*)d_in[10];

    char* ws = (char*)d_ws;
    size_t off = 0;
    auto alloc = [&](size_t bytes) -> void* {
        void* p = ws + off;
        off = (off + bytes + 255) & ~(size_t)255;
        return p;
    };
    float*  wq1     = (float*)alloc(144 * 4);
    ushort* wq2b    = (ushort*)alloc(4608 * 2);
    ushort* wq3b    = (ushort*)alloc(4608 * 2);
    float*  wqfc    = (float*)alloc(160 * 4);
    float*  wsb     = (float*)alloc(4 * 4);
    float*  partial = (float*)alloc(64 * 168 * 16 * 4);
    ushort* actA    = (ushort*)alloc(51380224ull * 2);
    ushort* actB    = (ushort*)alloc(51380224ull * 2);

    prep_kernel<<<4, 256, 0, stream>>>(c1w, c2w, c3w, fcw, asc, wq1, wq2b, wq3b, wqfc, wsb);
    conv1_kernel<<<3584, 448, 0, stream>>>(x, wq1, c1b, asc, shf, actA);
    conv16_kernel<false><<<10752, 256, 0, stream>>>(actA, wq2b, c2b, asc, shf, wsb,
                                                    actB, nullptr, 1, 1, 0);
    conv16_kernel<true ><<<10752, 256, 0, stream>>>(actB, wq3b, c3b, asc, shf, wsb,
                                                    nullptr, partial, 2, 2, 1);
    fc_kernel<<<1, 1024, 0, stream>>>(partial, wqfc, fcb, asc, (float*)d_out);
}